// Round 11
// baseline (467.109 us; speedup 1.0000x reference)
//
#include <hip/hip_runtime.h>
#include <hip/hip_fp16.h>
#include <cfloat>

#define BROWS 16384

typedef float f32x4 __attribute__((ext_vector_type(4)));
typedef _Float16 f16x8 __attribute__((ext_vector_type(8)));

// ---------- wave helpers ----------
__device__ __forceinline__ float wsum64(float v) {
#pragma unroll
  for (int off = 32; off; off >>= 1) v += __shfl_xor(v, off);
  return v;
}
__device__ __forceinline__ float wmax64(float v) {
#pragma unroll
  for (int off = 32; off; off >>= 1) v = fmaxf(v, __shfl_xor(v, off));
  return v;
}
__device__ __forceinline__ float gsum16(float v) {
#pragma unroll
  for (int off = 1; off < 16; off <<= 1) v += __shfl_xor(v, off);
  return v;
}

__device__ __forceinline__ float gelu_exact(float y) {
  return 0.5f * y * (1.f + erff(y * 0.70710678118654752f));
}

// fp16 2-limb split: v ~= h0 + 2^-11 * h1, residual <= 2^-24 |v|
__device__ __forceinline__ void split2(float v, unsigned short& o0, unsigned short& o1) {
  const _Float16 h0 = (_Float16)v;
  const float r = (v - (float)h0) * 2048.0f;
  const _Float16 h1 = (_Float16)r;
  o0 = __builtin_bit_cast(unsigned short, h0);
  o1 = __builtin_bit_cast(unsigned short, h1);
}

// async global -> LDS, 16B per lane, dest = wave-uniform base + lane*16
__device__ __forceinline__ void gll16(const unsigned short* g, unsigned short* l) {
  __builtin_amdgcn_global_load_lds(
      (const __attribute__((address_space(1))) unsigned int*)g,
      (__attribute__((address_space(3))) unsigned int*)l, 16, 0, 0);
}

// Combined swizzled plane format (2 fp16 limbs):
//   buf[(r*KT + kt)*64 + p*8 + s], physical chunk p = c ^ (r&7);
//   c 0..3 = limb0, c 4..7 = limb1. Conflict-free ds_read_b128.
__device__ __forceinline__ void write_chunks(
    unsigned short* __restrict__ P, size_t row, int KT, int kt, int c,
    const float* vals8) {
  unsigned short h0[8], h1[8];
#pragma unroll
  for (int s = 0; s < 8; ++s) split2(vals8[s], h0[s], h1[s]);
  const int r7 = (int)(row & 7);
  const size_t o = ((size_t)row * KT + kt) * 64;
  *(uint4*)&P[o + (size_t)((c ^ r7) * 8)] = *(const uint4*)h0;
  *(uint4*)&P[o + (size_t)(((4 + c) ^ r7) * 8)] = *(const uint4*)h1;
}

// ---------- 1) market encoder v3: K-split x row-split GEMV ----------
__global__ __launch_bounds__(256) void encoder_kernel(
    const float* __restrict__ x,
    const float* __restrict__ vol_w, const float* __restrict__ vol_b,
    const float* __restrict__ vol_g, const float* __restrict__ vol_bb,
    const float* __restrict__ trend_w, const float* __restrict__ trend_b,
    const float* __restrict__ trend_g, const float* __restrict__ trend_bb,
    const float* __restrict__ mom_w, const float* __restrict__ mom_b,
    const float* __restrict__ mom_g, const float* __restrict__ mom_bb,
    const float* __restrict__ reg_w, const float* __restrict__ reg_b,
    const float* __restrict__ reg_g, const float* __restrict__ reg_bb,
    const float* __restrict__ rc1_w, const float* __restrict__ rc1_b,
    const float* __restrict__ rc2_w, const float* __restrict__ rc2_b,
    const float* __restrict__ ns1_w, const float* __restrict__ ns1_b,
    const float* __restrict__ ns2_w, const float* __restrict__ ns2_b,
    float* __restrict__ rp4, float* __restrict__ nsc,
    unsigned short* __restrict__ gip) {
  __shared__ float sx[16][512];        // 32 KB
  __shared__ float spart[2][16][64];   // 8 KB
  __shared__ float smf[16][64];        // 4 KB
  __shared__ float shid[16][32];       // 2 KB
  __shared__ float srp[16][4];         // 256 B
  const int t = threadIdx.x;
  const int w = t >> 6;
  const int e = t & 63;
  const int br = e >> 4;
  const int rowbase0 = blockIdx.x * 16;

#pragma unroll
  for (int i = 0; i < 8; ++i) {
    const int f4 = t + i * 256;
    const int rr = f4 >> 7, cc = (f4 & 127) << 2;
    *(float4*)&sx[rr][cc] = *(const float4*)(x + ((size_t)rowbase0 + rr) * 512 + cc);
  }
  __syncthreads();

  const float* wsel = (br == 0) ? vol_w : (br == 1) ? trend_w : (br == 2) ? mom_w : reg_w;
  const float* bsel = (br == 0) ? vol_b : (br == 1) ? trend_b : (br == 2) ? mom_b : reg_b;
  const float* gsel = (br == 0) ? vol_g : (br == 1) ? trend_g : (br == 2) ? mom_g : reg_g;
  const float* bbsel = (br == 0) ? vol_bb : (br == 1) ? trend_bb : (br == 2) ? mom_bb : reg_bb;

  {
    const int kw = w >> 1, rg = w & 1;
    const int r0 = rg * 8;
    const float* wrow = wsel + (size_t)(e & 15) * 512 + kw * 256;
    float acc[8] = {};
#pragma unroll 2
    for (int i = 0; i < 64; ++i) {
      const float4 wv = *(const float4*)(wrow + i * 4);
#pragma unroll
      for (int r = 0; r < 8; ++r) {
        const float4 xv = *(const float4*)&sx[r0 + r][kw * 256 + i * 4];
        acc[r] += wv.x * xv.x + wv.y * xv.y + wv.z * xv.z + wv.w * xv.w;
      }
    }
#pragma unroll
    for (int r = 0; r < 8; ++r) spart[kw][r0 + r][e] = acc[r];
  }
  __syncthreads();

  const float bias = bsel[e & 15];
  const float gv = gsel[e & 15];
  const float bbv = bbsel[e & 15];
#pragma unroll
  for (int r = 0; r < 4; ++r) {
    const int row = w * 4 + r;
    const float raw = spart[0][row][e] + spart[1][row][e] + bias;
    const float v = fmaxf(raw, 0.f);
    const float mu = gsum16(v) * (1.f / 16.f);
    const float d = v - mu;
    const float var = gsum16(d * d) * (1.f / 16.f);
    smf[row][e] = d * (1.f / sqrtf(var + 1e-5f)) * gv + bbv;
  }
  __syncthreads();

  if (e < 32) {
#pragma unroll
    for (int r = 0; r < 4; ++r) {
      const int row = w * 4 + r;
      float h = rc1_b[e];
#pragma unroll 8
      for (int j = 0; j < 64; ++j) h += rc1_w[e * 64 + j] * smf[row][j];
      shid[row][e] = fmaxf(h, 0.f);
    }
  }
  __syncthreads();
  if (e < 16) {
    const int r = e >> 2, l = e & 3;
    const int row = w * 4 + r;
    float z = rc2_b[l];
#pragma unroll 8
    for (int j = 0; j < 32; ++j) z += rc2_w[l * 32 + j] * shid[row][j];
    float mx = z;
    mx = fmaxf(mx, __shfl_xor(mx, 1));
    mx = fmaxf(mx, __shfl_xor(mx, 2));
    const float ex = expf(z - mx);
    float s = ex;
    s += __shfl_xor(s, 1);
    s += __shfl_xor(s, 2);
    const float rp = ex / s;
    srp[row][l] = rp;
    rp4[(size_t)(rowbase0 + row) * 4 + l] = rp;
  }
  __syncthreads();
  if (e < 4) {
    const int row = w * 4 + e;
    const float rp0 = srp[row][0], rp1 = srp[row][1], rp2 = srp[row][2], rp3 = srp[row][3];
    float z = ns2_b[0];
#pragma unroll
    for (int i = 0; i < 16; ++i) {
      float h = ns1_b[i] + ns1_w[i * 4 + 0] * rp0 + ns1_w[i * 4 + 1] * rp1 +
                ns1_w[i * 4 + 2] * rp2 + ns1_w[i * 4 + 3] * rp3;
      z += ns2_w[i] * fmaxf(h, 0.f);
    }
    nsc[rowbase0 + row] = 1.f / (1.f + expf(-z));
  }
#pragma unroll
  for (int c = 0; c < 5; ++c) {
    const unsigned idx = (unsigned)t + c * 256u;
    const unsigned rib = idx / 80u;
    const unsigned item = idx - rib * 80u;
    const int kt = (int)(item >> 2), cch = (int)(item & 3);
    const size_t grow = (size_t)rowbase0 + rib;
    float v[8];
    const int kbase = kt * 32 + cch * 8;
    if (kbase < 512) {
      const float4 u0 = *(const float4*)&sx[rib][kbase];
      const float4 u1 = *(const float4*)&sx[rib][kbase + 4];
      v[0] = u0.x; v[1] = u0.y; v[2] = u0.z; v[3] = u0.w;
      v[4] = u1.x; v[5] = u1.y; v[6] = u1.z; v[7] = u1.w;
    } else {
#pragma unroll
      for (int s = 0; s < 8; ++s) {
        const int k = kbase + s;
        float f = 0.f;
        if (k < 576) f = smf[rib][k - 512];
        else if (k < 580) f = srp[rib][k - 576];
        v[s] = f;
      }
    }
    write_chunks(gip, grow, 20, kt, cch, v);
  }
}

// ---------- weight split: rows padded to Npad, cols to KT*32 ----------
__global__ __launch_bounds__(256) void split_w_v2(
    const float* __restrict__ W, unsigned short* __restrict__ P,
    int Nreal, int Kreal, int KT) {
  const unsigned idx = blockIdx.x * 256 + threadIdx.x;
  const unsigned ipr = (unsigned)(KT * 4);
  const unsigned row = idx / ipr;
  const unsigned item = idx - row * ipr;
  const int kt = item >> 2, c = item & 3;
  float v[8];
#pragma unroll
  for (int s = 0; s < 8; ++s) {
    const int k = kt * 32 + c * 8 + s;
    v[s] = ((int)row < Nreal && k < Kreal) ? W[(size_t)row * Kreal + k] : 0.f;
  }
  write_chunks(P, row, KT, kt, c, v);
}

// ---------- 2) fp16x3 MFMA GEMM v6: 256xTN tile, 3-phase interleave (m201-style) ----------
// C = A0B0 + 2^-11*(A1B0 + A0B1) + bias. 8 waves (512 thr) as 4M x 2N,
// per-wave 64 x TN/2. BK=32, 3-slot ring, counted vmcnt (NGLL/wave/stage).
// Per K-tile: 3 phases {ds_reads + staging-issue -> barrier -> lgkmcnt(0) ->
// setprio MFMA-cluster setprio -> barrier} so the MFMA pipe drains while the
// next phase's LDS/VMEM ops issue (m196/m201 mechanism).
template <int TN>
__global__ __launch_bounds__(512, 1) void gemm_fp16x3_v6(
    const unsigned short* __restrict__ Ap, const unsigned short* __restrict__ Bp,
    const float* __restrict__ bias, float* __restrict__ C,
    int N, int KT, int ldc, int nbx) {
  constexpr int NJ = TN / 32;              // j-frags per wave (4 or 2)
  constexpr int SLOTE = 16384 + TN * 64;   // ushorts per slot
  constexpr int NGLL = 4 + TN / 64;        // gll16 per wave per stage (6 or 5)
  extern __shared__ __align__(16) unsigned short smem[];
  const int t = threadIdx.x;
  const int wg = (blockIdx.x & 7) * ((int)gridDim.x >> 3) + (blockIdx.x >> 3);
  const int bx = wg % nbx, by = wg / nbx;
  const int m0 = by * 256, n0 = bx * TN;
  const int w = t >> 6, l = t & 63;
  const int lr = l & 15, lc = l >> 4;
  const int wm = (w >> 1) * 64, wn = (w & 1) * (TN / 2);

  const size_t stride = (size_t)KT * 64;
  size_t goff[6];
  int ldst[6];
#pragma unroll
  for (int c = 0; c < 4; ++c) {
    const int rb = w * 32 + c * 8;
    goff[c] = (size_t)(m0 + rb + (l >> 3)) * stride + (size_t)((l & 7) * 8);
    ldst[c] = rb * 64;
  }
#pragma unroll
  for (int c = 0; c < TN / 64; ++c) {
    const int rb = w * (TN / 8) + c * 8;
    goff[4 + c] = (size_t)(n0 + rb + (l >> 3)) * stride + (size_t)((l & 7) * 8);
    ldst[4 + c] = 16384 + rb * 64;
  }

  f32x4 accM[4][NJ], accL[4][NJ];
#pragma unroll
  for (int i = 0; i < 4; ++i)
#pragma unroll
    for (int j = 0; j < NJ; ++j) {
      accM[i][j] = (f32x4){0.f, 0.f, 0.f, 0.f};
      accL[i][j] = (f32x4){0.f, 0.f, 0.f, 0.f};
    }

  auto stage_one = [&](int kt2, int slot, int i) {
    const unsigned short* src = (i < 4) ? Ap : Bp;
    gll16(src + goff[i] + (size_t)kt2 * 64, smem + slot * SLOTE + ldst[i]);
  };

#pragma unroll
  for (int i = 0; i < NGLL; ++i) stage_one(0, 0, i);
#pragma unroll
  for (int i = 0; i < NGLL; ++i) stage_one(1, 1, i);

  int scur = 0;
  for (int kt = 0; kt < KT; ++kt) {
    // slot `scur` data (staged 2 iters ago) must be complete; t+1's NGLL stay in flight
    if (kt + 1 < KT) {
      if (TN == 128) asm volatile("s_waitcnt vmcnt(6)" ::: "memory");
      else           asm volatile("s_waitcnt vmcnt(5)" ::: "memory");
    } else {
      asm volatile("s_waitcnt vmcnt(0)" ::: "memory");
    }
    __builtin_amdgcn_sched_barrier(0);
    __builtin_amdgcn_s_barrier();
    __builtin_amdgcn_sched_barrier(0);

    const unsigned short* base = smem + scur * SLOTE;
    const int sprf = (scur + 2 >= 3) ? (scur - 1) : (scur + 2);
    const bool pf = (kt + 2 < KT);
    f16x8 a0[4], a1[4], b0[NJ], b1[NJ];

    // ---- phase 0: read a0,b0 ; stage pair 0,1 ; MFMA M += a0*b0 ----
#pragma unroll
    for (int i = 0; i < 4; ++i) {
      const int ar = wm + i * 16 + lr;
      a0[i] = *(const f16x8*)&base[ar * 64 + (((lc) ^ (ar & 7)) << 3)];
    }
#pragma unroll
    for (int j = 0; j < NJ; ++j) {
      const int brj = wn + j * 16 + lr;
      b0[j] = *(const f16x8*)&base[16384 + brj * 64 + (((lc) ^ (brj & 7)) << 3)];
    }
    if (pf) { stage_one(kt + 2, sprf, 0); stage_one(kt + 2, sprf, 1); }
    __builtin_amdgcn_sched_barrier(0);
    __builtin_amdgcn_s_barrier();
    asm volatile("s_waitcnt lgkmcnt(0)" ::: "memory");
    __builtin_amdgcn_sched_barrier(0);
    __builtin_amdgcn_s_setprio(1);
#pragma unroll
    for (int i = 0; i < 4; ++i)
#pragma unroll
      for (int j = 0; j < NJ; ++j)
        accM[i][j] = __builtin_amdgcn_mfma_f32_16x16x32_f16(a0[i], b0[j], accM[i][j], 0, 0, 0);
    __builtin_amdgcn_s_setprio(0);
    __builtin_amdgcn_s_barrier();

    // ---- phase 1: read a1 ; stage pair 2,3 ; MFMA L += a1*b0 ----
#pragma unroll
    for (int i = 0; i < 4; ++i) {
      const int ar = wm + i * 16 + lr;
      a1[i] = *(const f16x8*)&base[ar * 64 + (((4 + lc) ^ (ar & 7)) << 3)];
    }
    if (pf) { stage_one(kt + 2, sprf, 2); stage_one(kt + 2, sprf, 3); }
    __builtin_amdgcn_sched_barrier(0);
    __builtin_amdgcn_s_barrier();
    asm volatile("s_waitcnt lgkmcnt(0)" ::: "memory");
    __builtin_amdgcn_sched_barrier(0);
    __builtin_amdgcn_s_setprio(1);
#pragma unroll
    for (int i = 0; i < 4; ++i)
#pragma unroll
      for (int j = 0; j < NJ; ++j)
        accL[i][j] = __builtin_amdgcn_mfma_f32_16x16x32_f16(a1[i], b0[j], accL[i][j], 0, 0, 0);
    __builtin_amdgcn_s_setprio(0);
    __builtin_amdgcn_s_barrier();

    // ---- phase 2: read b1 ; stage pair 4(,5) ; MFMA L += a0*b1 ----
#pragma unroll
    for (int j = 0; j < NJ; ++j) {
      const int brj = wn + j * 16 + lr;
      b1[j] = *(const f16x8*)&base[16384 + brj * 64 + (((4 + lc) ^ (brj & 7)) << 3)];
    }
    if (pf) {
      stage_one(kt + 2, sprf, 4);
      if (TN == 128) stage_one(kt + 2, sprf, 5);
    }
    __builtin_amdgcn_sched_barrier(0);
    __builtin_amdgcn_s_barrier();
    asm volatile("s_waitcnt lgkmcnt(0)" ::: "memory");
    __builtin_amdgcn_sched_barrier(0);
    __builtin_amdgcn_s_setprio(1);
#pragma unroll
    for (int i = 0; i < 4; ++i)
#pragma unroll
      for (int j = 0; j < NJ; ++j)
        accL[i][j] = __builtin_amdgcn_mfma_f32_16x16x32_f16(a0[i], b1[j], accL[i][j], 0, 0, 0);
    __builtin_amdgcn_s_setprio(0);
    __builtin_amdgcn_s_barrier();

    scur = (scur + 1 == 3) ? 0 : scur + 1;
  }
  // epilogue: D layout col(lane&15)=n, row((lane>>4)*4+reg)=m
#pragma unroll
  for (int j = 0; j < NJ; ++j) {
    const int n = n0 + wn + j * 16 + lr;
    if (n < N) {
      const float bz = bias[n];
#pragma unroll
      for (int i = 0; i < 4; ++i) {
        const int mb = m0 + wm + i * 16 + lc * 4;
#pragma unroll
        for (int r = 0; r < 4; ++r)
          C[(size_t)(mb + r) * (size_t)ldc + n] =
              accM[i][j][r] + 0.00048828125f * accL[i][j][r] + bz;
      }
    }
  }
}

// ---------- 2b) G3 fused: row-LN + exact GELU + fp32 64x64 GEMM ----------
__global__ __launch_bounds__(256, 4) void gemm64_ln_kernel(
    const float* __restrict__ Zraw, const float* __restrict__ gamma,
    const float* __restrict__ beta, const float* __restrict__ W,
    const float* __restrict__ bias, float* __restrict__ C) {
  const int K = 580, N = 64;
  __shared__ float As[16][68];
  __shared__ float Bs[16][68];
  __shared__ float sg[580], sb[580], smu[64], srs[64];
  const int t = threadIdx.x;
  const int m0 = blockIdx.x * 64;
  for (int i = t; i < 580; i += 256) { sg[i] = gamma[i]; sb[i] = beta[i]; }
  const int r = t >> 2, q = t & 3;
  const float* zr = Zraw + (size_t)(m0 + r) * K;
  float s0 = 0.f, s1 = 0.f, ss0 = 0.f, ss1 = 0.f;
  for (int j = q; j < 145; j += 8) {
    const float4 u = *(const float4*)(zr + j * 4);
    s0 += u.x + u.y + u.z + u.w;
    ss0 += u.x * u.x + u.y * u.y + u.z * u.z + u.w * u.w;
  }
  for (int j = q + 4; j < 145; j += 8) {
    const float4 u = *(const float4*)(zr + j * 4);
    s1 += u.x + u.y + u.z + u.w;
    ss1 += u.x * u.x + u.y * u.y + u.z * u.z + u.w * u.w;
  }
  float s = s0 + s1, ss = ss0 + ss1;
  s += __shfl_xor(s, 1); s += __shfl_xor(s, 2);
  ss += __shfl_xor(ss, 1); ss += __shfl_xor(ss, 2);
  const float mu = s * (1.f / 580.f);
  const float var = fmaxf(ss * (1.f / 580.f) - mu * mu, 0.f);
  if (q == 0) { smu[r] = mu; srs[r] = 1.f / sqrtf(var + 1e-5f); }
  __syncthreads();

  const int tx = t & 15, ty = t >> 4;
  float acc[4][4] = {};
  for (int kt = 0; kt < 37; ++kt) {
    const int k = kt * 16 + (q << 2);
    float4 va = {0.f, 0.f, 0.f, 0.f}, vb = {0.f, 0.f, 0.f, 0.f};
    if (k < K) {
      const float4 z = *(const float4*)(zr + k);
      const float m_ = smu[r], rs = srs[r];
      va.x = gelu_exact((z.x - m_) * rs * sg[k + 0] + sb[k + 0]);
      va.y = gelu_exact((z.y - m_) * rs * sg[k + 1] + sb[k + 1]);
      va.z = gelu_exact((z.z - m_) * rs * sg[k + 2] + sb[k + 2]);
      va.w = gelu_exact((z.w - m_) * rs * sg[k + 3] + sb[k + 3]);
      vb = *(const float4*)(W + (size_t)r * K + k);
    }
    __syncthreads();
    const int skc = q << 2;
    As[skc + 0][r] = va.x; As[skc + 1][r] = va.y;
    As[skc + 2][r] = va.z; As[skc + 3][r] = va.w;
    Bs[skc + 0][r] = vb.x; Bs[skc + 1][r] = vb.y;
    Bs[skc + 2][r] = vb.z; Bs[skc + 3][r] = vb.w;
    __syncthreads();
#pragma unroll
    for (int kk = 0; kk < 16; ++kk) {
      const float4 a = *(const float4*)&As[kk][ty << 2];
      const float4 b = *(const float4*)&Bs[kk][tx << 2];
      const float aa[4] = {a.x, a.y, a.z, a.w};
      const float bb[4] = {b.x, b.y, b.z, b.w};
#pragma unroll
      for (int i = 0; i < 4; ++i)
#pragma unroll
        for (int j = 0; j < 4; ++j) acc[i][j] = fmaf(aa[i], bb[j], acc[i][j]);
    }
  }
  const float4 bz = *(const float4*)(bias + (tx << 2));
#pragma unroll
  for (int i = 0; i < 4; ++i) {
    const int m = m0 + (ty << 2) + i;
    float4 o;
    o.x = acc[i][0] + bz.x; o.y = acc[i][1] + bz.y;
    o.z = acc[i][2] + bz.z; o.w = acc[i][3] + bz.w;
    *(float4*)(C + (size_t)m * N + (tx << 2)) = o;
  }
}

// ---------- 3) row LN + exact GELU -> swizzled planes (z1); 1 wave = 1 row ----------
__global__ __launch_bounds__(256) void ln_gelu_split_v3(
    const float* __restrict__ Z, const float* __restrict__ gamma,
    const float* __restrict__ beta, unsigned short* __restrict__ P) {
  const int N = 1160, KT = 38;
  __shared__ float srow[4][1160];
  const int t = threadIdx.x, w = t >> 6, l = t & 63;
  const size_t row = (size_t)blockIdx.x * 4 + w;
  const float* zr = Z + row * N;
  float4 v[5];
  float s = 0.f;
#pragma unroll
  for (int c = 0; c < 5; ++c) {
    const int i4 = l + c * 64;
    if (i4 < 290) {
      v[c] = *(const float4*)(zr + i4 * 4);
      *(float4*)&srow[w][i4 * 4] = v[c];
      s += v[c].x + v[c].y + v[c].z + v[c].w;
    } else {
      v[c] = {0.f, 0.f, 0.f, 0.f};
    }
  }
  s = wsum64(s);
  const float mu = s * (1.f / 1160.f);
  float q = 0.f;
#pragma unroll
  for (int c = 0; c < 5; ++c) {
    const int i4 = l + c * 64;
    if (i4 < 290) {
      const float dx = v[c].x - mu, dy = v[c].y - mu, dz = v[c].z - mu, dw = v[c].w - mu;
      q += dx * dx + dy * dy + dz * dz + dw * dw;
    }
  }
  q = wsum64(q);
  const float rstd = 1.f / sqrtf(q * (1.f / 1160.f) + 1e-5f);
  __syncthreads();
  for (int ch = l; ch < 152; ch += 64) {
    const int kt = ch >> 2, c = ch & 3;
    float vv[8];
#pragma unroll
    for (int s2 = 0; s2 < 8; ++s2) {
      const int k = kt * 32 + c * 8 + s2;
      float g = 0.f;
      if (k < N) {
        const float y = (srow[w][k] - mu) * rstd * gamma[k] + beta[k];
        g = gelu_exact(y);
      }
      vv[s2] = g;
    }
    write_chunks(P, row, KT, kt, c, vv);
  }
}

// ---------- 4) final: +rp*spec^T, noise, top-2, gates, partials ----------
__global__ __launch_bounds__(256) void final_kernel(
    const float* __restrict__ clean, const float* __restrict__ rp4,
    const float* __restrict__ nsc, const float* __restrict__ noise,
    const float* __restrict__ spec, float* __restrict__ out,
    float* __restrict__ pg, float* __restrict__ pl) {
  const int t = threadIdx.x;
  const int w = t >> 6;
  const int e = t & 63;
  __shared__ float sg[4][64];
  __shared__ float sl[4][64];
  const float4 sp = *(const float4*)(spec + e * 4);
  float accg = 0.f, accl = 0.f;
  for (int it = 0; it < 16; ++it) {
    const int row = blockIdx.x * 64 + it * 4 + w;
    const float4 rp = *(const float4*)(rp4 + (size_t)row * 4);
    float c = clean[(size_t)row * 64 + e];
    c += rp.x * sp.x + rp.y * sp.y + rp.z * sp.z + rp.w * sp.w;
    const float nv = noise[(size_t)row * 64 + e];
    const float noisy = c + nv * nsc[row];
    float v = noisy;
    int ix = e;
#pragma unroll
    for (int off = 32; off; off >>= 1) {
      const float ov = __shfl_xor(v, off);
      const int oi = __shfl_xor(ix, off);
      if (ov > v || (ov == v && oi < ix)) { v = ov; ix = oi; }
    }
    const float v1 = v;
    const int i1 = ix;
    float v2 = (e == i1) ? -FLT_MAX : noisy;
    int ix2 = e;
#pragma unroll
    for (int off = 32; off; off >>= 1) {
      const float ov = __shfl_xor(v2, off);
      const int oi = __shfl_xor(ix2, off);
      if (ov > v2 || (ov == v2 && oi < ix2)) { v2 = ov; ix2 = oi; }
    }
    const int i2 = ix2;
    if (e == 0) {
      const float texp = expf(v2 - v1);
      const float tw0 = 1.f / (1.f + texp);
      out[(size_t)row * 2 + 0] = tw0;
      out[(size_t)row * 2 + 1] = texp * tw0;
      out[32768 + (size_t)row * 2 + 0] = (float)i1;
      out[32768 + (size_t)row * 2 + 1] = (float)i2;
    }
    const float mx = wmax64(c);
    const float p = expf(c - mx);
    const float ssum = wsum64(p);
    accg += p / ssum;
    accl += (e == i1 || e == i2) ? 1.f : 0.f;
  }
  sg[w][e] = accg;
  sl[w][e] = accl;
  __syncthreads();
  if (t < 64) {
    pg[blockIdx.x * 64 + t] = sg[0][t] + sg[1][t] + sg[2][t] + sg[3][t];
    pl[blockIdx.x * 64 + t] = sl[0][t] + sl[1][t] + sl[2][t] + sl[3][t];
  }
}

// ---------- 5) aux loss ----------
__global__ void loss_kernel(const float* __restrict__ pg,
                            const float* __restrict__ pl,
                            float* __restrict__ out) {
  const int e = threadIdx.x;  // 64 threads
  float g = 0.f, l = 0.f;
  for (int b = 0; b < 256; ++b) {
    g += pg[b * 64 + e];
    l += pl[b * 64 + e];
  }
  const float prob = g * (1.f / 16384.f);
  const float ld = l * (1.f / 16384.f);
  const float load_loss = 64.f * wsum64(prob * ld);
  const float sgs = wsum64(g);
  const float mean = sgs * (1.f / 64.f);
  const float d = g - mean;
  const float var = wsum64(d * d) * (1.f / 63.f);
  if (e == 0) out[65536] = 0.01f * load_loss + 0.01f * (var / mean);
}

extern "C" void kernel_launch(void* const* d_in, const int* in_sizes, int n_in,
                              void* d_out, int out_size, void* d_ws, size_t ws_size,
                              hipStream_t stream) {
  (void)in_sizes; (void)n_in; (void)out_size; (void)ws_size;
  const float* x = (const float*)d_in[0];
  const float* noise = (const float*)d_in[1];
  const float* vol_w = (const float*)d_in[2];
  const float* vol_b = (const float*)d_in[3];
  const float* vol_g = (const float*)d_in[4];
  const float* vol_bb = (const float*)d_in[5];
  const float* trend_w = (const float*)d_in[6];
  const float* trend_b = (const float*)d_in[7];
  const float* trend_g = (const float*)d_in[8];
  const float* trend_bb = (const float*)d_in[9];
  const float* mom_w = (const float*)d_in[10];
  const float* mom_b = (const float*)d_in[11];
  const float* mom_g = (const float*)d_in[12];
  const float* mom_bb = (const float*)d_in[13];
  const float* reg_w = (const float*)d_in[14];
  const float* reg_b = (const float*)d_in[15];
  const float* reg_g = (const float*)d_in[16];
  const float* reg_bb = (const float*)d_in[17];
  const float* rc1_w = (const float*)d_in[18];
  const float* rc1_b = (const float*)d_in[19];
  const float* rc2_w = (const float*)d_in[20];
  const float* rc2_b = (const float*)d_in[21];
  const float* g1_w = (const float*)d_in[22];
  const float* g1_b = (const float*)d_in[23];
  const float* g1_g = (const float*)d_in[24];
  const float* g1_bb = (const float*)d_in[25];
  const float* g2_w = (const float*)d_in[26];
  const float* g2_b = (const float*)d_in[27];
  const float* g2_g = (const float*)d_in[28];
  const float* g2_bb = (const float*)d_in[29];
  const float* g3_w = (const float*)d_in[30];
  const float* g3_b = (const float*)d_in[31];
  const float* ns1_w = (const float*)d_in[32];
  const float* ns1_b = (const float*)d_in[33];
  const float* ns2_w = (const float*)d_in[34];
  const float* ns2_b = (const float*)d_in[35];
  const float* spec = (const float*)d_in[36];
  float* out = (float*)d_out;

  const size_t B = BROWS;
  float* ws = (float*)d_ws;
  float* rp4 = ws;                                    // B*4 f32
  float* nsc = rp4 + B * 4;                           // B f32
  float* z1 = nsc + B;                                // B*1160 f32
  unsigned short* gip = (unsigned short*)(z1 + B * 1160);  // B*1280 ush (KT=20)
  float* z2 = (float*)gip;                            // alias: B*580 f32 (gi dead after G1)
  unsigned short* z1p = gip + B * 1280;               // B*2432 ush (KT=38)
  unsigned short* w1p = z1p + B * 2432;               // 1280*1280 ush
  unsigned short* w2p = w1p + (size_t)1280 * 1280;    // 640*2432 ush
  float* cln = (float*)(w2p + (size_t)640 * 2432);    // B*64 f32
  float* pg = cln + B * 64;                           // 256*64
  float* pl = pg + 256 * 64;                          // 256*64

  hipFuncSetAttribute(reinterpret_cast<const void*>(&gemm_fp16x3_v6<128>),
                      hipFuncAttributeMaxDynamicSharedMemorySize, 147456);
  hipFuncSetAttribute(reinterpret_cast<const void*>(&gemm_fp16x3_v6<64>),
                      hipFuncAttributeMaxDynamicSharedMemorySize, 122880);

  // weights -> swizzled planes (W1: Npad=1280,KT=20; W2: Npad=640,KT=38)
  split_w_v2<<<400, 256, 0, stream>>>(g1_w, w1p, 1160, 580, 20);
  split_w_v2<<<380, 256, 0, stream>>>(g2_w, w2p, 580, 1160, 38);

  encoder_kernel<<<1024, 256, 0, stream>>>(
      x, vol_w, vol_b, vol_g, vol_bb, trend_w, trend_b, trend_g, trend_bb,
      mom_w, mom_b, mom_g, mom_bb, reg_w, reg_b, reg_g, reg_bb,
      rc1_w, rc1_b, rc2_w, rc2_b, ns1_w, ns1_b, ns2_w, ns2_b, rp4, nsc, gip);

  // G1: [16384,640] x [1280,640]^T -> z1 ; tile 256x128, grid 64 m x 10 n = 640
  gemm_fp16x3_v6<128><<<640, 512, 147456, stream>>>(
      gip, w1p, g1_b, z1, 1160, 20, 1160, 10);
  ln_gelu_split_v3<<<4096, 256, 0, stream>>>(z1, g1_g, g1_bb, z1p);

  // G2: [16384,1216] x [640,1216]^T -> z2 ; tile 256x64, grid 64 m x 10 n = 640
  gemm_fp16x3_v6<64><<<640, 512, 122880, stream>>>(
      z1p, w2p, g2_b, z2, 580, 38, 580, 10);

  // G3 fused LN+GELU+GEMM: z2 -> clean
  gemm64_ln_kernel<<<256, 256, 0, stream>>>(z2, g2_g, g2_bb, g3_w, g3_b, cln);

  final_kernel<<<256, 256, 0, stream>>>(cln, rp4, nsc, noise, spec, out, pg, pl);
  loss_kernel<<<1, 64, 0, stream>>>(pg, pl, out);
}

// Round 13
// 449.433 us; speedup vs baseline: 1.0393x; 1.0393x over previous
//
#include <hip/hip_runtime.h>
#include <hip/hip_fp16.h>
#include <cfloat>

#define BROWS 16384

typedef float f32x4 __attribute__((ext_vector_type(4)));
typedef _Float16 f16x8 __attribute__((ext_vector_type(8)));

// ---------- wave helpers ----------
__device__ __forceinline__ float wsum64(float v) {
#pragma unroll
  for (int off = 32; off; off >>= 1) v += __shfl_xor(v, off);
  return v;
}
__device__ __forceinline__ float wmax64(float v) {
#pragma unroll
  for (int off = 32; off; off >>= 1) v = fmaxf(v, __shfl_xor(v, off));
  return v;
}
__device__ __forceinline__ float gsum16(float v) {
#pragma unroll
  for (int off = 1; off < 16; off <<= 1) v += __shfl_xor(v, off);
  return v;
}

__device__ __forceinline__ float gelu_exact(float y) {
  return 0.5f * y * (1.f + erff(y * 0.70710678118654752f));
}

// fp16 2-limb split: v ~= h0 + 2^-11 * h1, residual <= 2^-24 |v|
__device__ __forceinline__ void split2(float v, unsigned short& o0, unsigned short& o1) {
  const _Float16 h0 = (_Float16)v;
  const float r = (v - (float)h0) * 2048.0f;
  const _Float16 h1 = (_Float16)r;
  o0 = __builtin_bit_cast(unsigned short, h0);
  o1 = __builtin_bit_cast(unsigned short, h1);
}

// async global -> LDS, 16B per lane, dest = wave-uniform base + lane*16
__device__ __forceinline__ void gll16(const unsigned short* g, unsigned short* l) {
  __builtin_amdgcn_global_load_lds(
      (const __attribute__((address_space(1))) unsigned int*)g,
      (__attribute__((address_space(3))) unsigned int*)l, 16, 0, 0);
}

// Combined swizzled plane format (2 fp16 limbs):
//   buf[(r*KT + kt)*64 + p*8 + s], physical chunk p = c ^ (r&7);
//   c 0..3 = limb0, c 4..7 = limb1. Conflict-free ds_read_b128.
__device__ __forceinline__ void write_chunks(
    unsigned short* __restrict__ P, size_t row, int KT, int kt, int c,
    const float* vals8) {
  unsigned short h0[8], h1[8];
#pragma unroll
  for (int s = 0; s < 8; ++s) split2(vals8[s], h0[s], h1[s]);
  const int r7 = (int)(row & 7);
  const size_t o = ((size_t)row * KT + kt) * 64;
  *(uint4*)&P[o + (size_t)((c ^ r7) * 8)] = *(const uint4*)h0;
  *(uint4*)&P[o + (size_t)(((4 + c) ^ r7) * 8)] = *(const uint4*)h1;
}

// ---------- 1) market encoder v3: K-split x row-split GEMV ----------
__global__ __launch_bounds__(256) void encoder_kernel(
    const float* __restrict__ x,
    const float* __restrict__ vol_w, const float* __restrict__ vol_b,
    const float* __restrict__ vol_g, const float* __restrict__ vol_bb,
    const float* __restrict__ trend_w, const float* __restrict__ trend_b,
    const float* __restrict__ trend_g, const float* __restrict__ trend_bb,
    const float* __restrict__ mom_w, const float* __restrict__ mom_b,
    const float* __restrict__ mom_g, const float* __restrict__ mom_bb,
    const float* __restrict__ reg_w, const float* __restrict__ reg_b,
    const float* __restrict__ reg_g, const float* __restrict__ reg_bb,
    const float* __restrict__ rc1_w, const float* __restrict__ rc1_b,
    const float* __restrict__ rc2_w, const float* __restrict__ rc2_b,
    const float* __restrict__ ns1_w, const float* __restrict__ ns1_b,
    const float* __restrict__ ns2_w, const float* __restrict__ ns2_b,
    float* __restrict__ rp4, float* __restrict__ nsc,
    unsigned short* __restrict__ gip) {
  __shared__ float sx[16][512];        // 32 KB
  __shared__ float spart[2][16][64];   // 8 KB
  __shared__ float smf[16][64];        // 4 KB
  __shared__ float shid[16][32];       // 2 KB
  __shared__ float srp[16][4];         // 256 B
  const int t = threadIdx.x;
  const int w = t >> 6;
  const int e = t & 63;
  const int br = e >> 4;
  const int rowbase0 = blockIdx.x * 16;

#pragma unroll
  for (int i = 0; i < 8; ++i) {
    const int f4 = t + i * 256;
    const int rr = f4 >> 7, cc = (f4 & 127) << 2;
    *(float4*)&sx[rr][cc] = *(const float4*)(x + ((size_t)rowbase0 + rr) * 512 + cc);
  }
  __syncthreads();

  const float* wsel = (br == 0) ? vol_w : (br == 1) ? trend_w : (br == 2) ? mom_w : reg_w;
  const float* bsel = (br == 0) ? vol_b : (br == 1) ? trend_b : (br == 2) ? mom_b : reg_b;
  const float* gsel = (br == 0) ? vol_g : (br == 1) ? trend_g : (br == 2) ? mom_g : reg_g;
  const float* bbsel = (br == 0) ? vol_bb : (br == 1) ? trend_bb : (br == 2) ? mom_bb : reg_bb;

  {
    const int kw = w >> 1, rg = w & 1;
    const int r0 = rg * 8;
    const float* wrow = wsel + (size_t)(e & 15) * 512 + kw * 256;
    float acc[8] = {};
#pragma unroll 2
    for (int i = 0; i < 64; ++i) {
      const float4 wv = *(const float4*)(wrow + i * 4);
#pragma unroll
      for (int r = 0; r < 8; ++r) {
        const float4 xv = *(const float4*)&sx[r0 + r][kw * 256 + i * 4];
        acc[r] += wv.x * xv.x + wv.y * xv.y + wv.z * xv.z + wv.w * xv.w;
      }
    }
#pragma unroll
    for (int r = 0; r < 8; ++r) spart[kw][r0 + r][e] = acc[r];
  }
  __syncthreads();

  const float bias = bsel[e & 15];
  const float gv = gsel[e & 15];
  const float bbv = bbsel[e & 15];
#pragma unroll
  for (int r = 0; r < 4; ++r) {
    const int row = w * 4 + r;
    const float raw = spart[0][row][e] + spart[1][row][e] + bias;
    const float v = fmaxf(raw, 0.f);
    const float mu = gsum16(v) * (1.f / 16.f);
    const float d = v - mu;
    const float var = gsum16(d * d) * (1.f / 16.f);
    smf[row][e] = d * (1.f / sqrtf(var + 1e-5f)) * gv + bbv;
  }
  __syncthreads();

  if (e < 32) {
#pragma unroll
    for (int r = 0; r < 4; ++r) {
      const int row = w * 4 + r;
      float h = rc1_b[e];
#pragma unroll 8
      for (int j = 0; j < 64; ++j) h += rc1_w[e * 64 + j] * smf[row][j];
      shid[row][e] = fmaxf(h, 0.f);
    }
  }
  __syncthreads();
  if (e < 16) {
    const int r = e >> 2, l = e & 3;
    const int row = w * 4 + r;
    float z = rc2_b[l];
#pragma unroll 8
    for (int j = 0; j < 32; ++j) z += rc2_w[l * 32 + j] * shid[row][j];
    float mx = z;
    mx = fmaxf(mx, __shfl_xor(mx, 1));
    mx = fmaxf(mx, __shfl_xor(mx, 2));
    const float ex = expf(z - mx);
    float s = ex;
    s += __shfl_xor(s, 1);
    s += __shfl_xor(s, 2);
    const float rp = ex / s;
    srp[row][l] = rp;
    rp4[(size_t)(rowbase0 + row) * 4 + l] = rp;
  }
  __syncthreads();
  if (e < 4) {
    const int row = w * 4 + e;
    const float rp0 = srp[row][0], rp1 = srp[row][1], rp2 = srp[row][2], rp3 = srp[row][3];
    float z = ns2_b[0];
#pragma unroll
    for (int i = 0; i < 16; ++i) {
      float h = ns1_b[i] + ns1_w[i * 4 + 0] * rp0 + ns1_w[i * 4 + 1] * rp1 +
                ns1_w[i * 4 + 2] * rp2 + ns1_w[i * 4 + 3] * rp3;
      z += ns2_w[i] * fmaxf(h, 0.f);
    }
    nsc[rowbase0 + row] = 1.f / (1.f + expf(-z));
  }
#pragma unroll
  for (int c = 0; c < 5; ++c) {
    const unsigned idx = (unsigned)t + c * 256u;
    const unsigned rib = idx / 80u;
    const unsigned item = idx - rib * 80u;
    const int kt = (int)(item >> 2), cch = (int)(item & 3);
    const size_t grow = (size_t)rowbase0 + rib;
    float v[8];
    const int kbase = kt * 32 + cch * 8;
    if (kbase < 512) {
      const float4 u0 = *(const float4*)&sx[rib][kbase];
      const float4 u1 = *(const float4*)&sx[rib][kbase + 4];
      v[0] = u0.x; v[1] = u0.y; v[2] = u0.z; v[3] = u0.w;
      v[4] = u1.x; v[5] = u1.y; v[6] = u1.z; v[7] = u1.w;
    } else {
#pragma unroll
      for (int s = 0; s < 8; ++s) {
        const int k = kbase + s;
        float f = 0.f;
        if (k < 576) f = smf[rib][k - 512];
        else if (k < 580) f = srp[rib][k - 576];
        v[s] = f;
      }
    }
    write_chunks(gip, grow, 20, kt, cch, v);
  }
}

// ---------- weight splits, both matrices in one launch ----------
__device__ __forceinline__ void split_w_body(
    const float* __restrict__ W, unsigned short* __restrict__ P,
    unsigned idx, int Nreal, int Kreal, int KT) {
  const unsigned ipr = (unsigned)(KT * 4);
  const unsigned row = idx / ipr;
  const unsigned item = idx - row * ipr;
  const int kt = item >> 2, c = item & 3;
  float v[8];
#pragma unroll
  for (int s = 0; s < 8; ++s) {
    const int k = kt * 32 + c * 8 + s;
    v[s] = ((int)row < Nreal && k < Kreal) ? W[(size_t)row * Kreal + k] : 0.f;
  }
  write_chunks(P, row, KT, kt, c, v);
}

__global__ __launch_bounds__(256) void split_w_both(
    const float* __restrict__ W1, unsigned short* __restrict__ P1,
    const float* __restrict__ W2, unsigned short* __restrict__ P2) {
  const unsigned bid = blockIdx.x;
  if (bid < 400) {  // W1: Npad=1280, KT=20 -> 400*256 items
    split_w_body(W1, P1, bid * 256 + threadIdx.x, 1160, 580, 20);
  } else {          // W2: Npad=640, KT=38 -> 380*256 items
    split_w_body(W2, P2, (bid - 400) * 256 + threadIdx.x, 580, 1160, 38);
  }
}

// ---------- 2) fp16x3 MFMA GEMM v4 (proven R7-R9): 3-slot ring, d=2, vmcnt(4) ----------
__global__ __launch_bounds__(512, 1) void gemm_fp16x3_v4(
    const unsigned short* __restrict__ Ap, const unsigned short* __restrict__ Bp,
    const float* __restrict__ bias, float* __restrict__ C,
    int N, int KT, int ldc, int nbx) {
  extern __shared__ __align__(16) unsigned short smem[];  // 3 * 16384 ushorts
  const int t = threadIdx.x;
  const int wg = (blockIdx.x & 7) * ((int)gridDim.x >> 3) + (blockIdx.x >> 3);
  const int bx = wg % nbx, by = wg / nbx;
  const int m0 = by * 128, n0 = bx * 128;
  const int w = t >> 6, l = t & 63;
  const int lr = l & 15, lc = l >> 4;
  const int wm = (w >> 2) * 64, wn = (w & 3) * 32;

  const size_t stride = (size_t)KT * 64;
  size_t aoff[2], boff[2];
#pragma unroll
  for (int c = 0; c < 2; ++c) {
    const int rb = w * 16 + c * 8;
    aoff[c] = (size_t)(m0 + rb + (l >> 3)) * stride + (size_t)((l & 7) * 8);
    boff[c] = (size_t)(n0 + rb + (l >> 3)) * stride + (size_t)((l & 7) * 8);
  }

  f32x4 accM[4][2], accL[4][2];
#pragma unroll
  for (int i = 0; i < 4; ++i)
#pragma unroll
    for (int j = 0; j < 2; ++j) {
      accM[i][j] = (f32x4){0.f, 0.f, 0.f, 0.f};
      accL[i][j] = (f32x4){0.f, 0.f, 0.f, 0.f};
    }

  auto stage = [&](int kt, int slot) {
    unsigned short* base = smem + slot * 16384;
    const size_t ko = (size_t)kt * 64;
#pragma unroll
    for (int c = 0; c < 2; ++c) {
      const int rb = w * 16 + c * 8;
      gll16(Ap + aoff[c] + ko, base + rb * 64);
      gll16(Bp + boff[c] + ko, base + 8192 + rb * 64);
    }
  };

  stage(0, 0);
  stage(1, 1);
  asm volatile("s_waitcnt vmcnt(4)" ::: "memory");
  __builtin_amdgcn_sched_barrier(0);
  __builtin_amdgcn_s_barrier();
  __builtin_amdgcn_sched_barrier(0);

  int scur = 0;
  for (int kt = 0; kt < KT; ++kt) {
    const int sprf = (scur + 2 >= 3) ? (scur - 1) : (scur + 2);
    if (kt + 2 < KT) {
      stage(kt + 2, sprf);
      __builtin_amdgcn_sched_barrier(0);
    }
    const unsigned short* base = smem + scur * 16384;
    f16x8 a0[4], a1[4], b0[2], b1[2];
#pragma unroll
    for (int i = 0; i < 4; ++i) {
      const int ar = wm + i * 16 + lr;
      const int r7 = ar & 7;
      a0[i] = *(const f16x8*)&base[ar * 64 + ((lc ^ r7) << 3)];
      a1[i] = *(const f16x8*)&base[ar * 64 + (((4 + lc) ^ r7) << 3)];
    }
#pragma unroll
    for (int j = 0; j < 2; ++j) {
      const int brj = wn + j * 16 + lr;
      const int r7 = brj & 7;
      b0[j] = *(const f16x8*)&base[8192 + brj * 64 + ((lc ^ r7) << 3)];
      b1[j] = *(const f16x8*)&base[8192 + brj * 64 + (((4 + lc) ^ r7) << 3)];
    }
    __builtin_amdgcn_s_setprio(1);
#pragma unroll
    for (int i = 0; i < 4; ++i)
#pragma unroll
      for (int j = 0; j < 2; ++j)
        accM[i][j] = __builtin_amdgcn_mfma_f32_16x16x32_f16(a0[i], b0[j], accM[i][j], 0, 0, 0);
#pragma unroll
    for (int i = 0; i < 4; ++i)
#pragma unroll
      for (int j = 0; j < 2; ++j)
        accL[i][j] = __builtin_amdgcn_mfma_f32_16x16x32_f16(a1[i], b0[j], accL[i][j], 0, 0, 0);
#pragma unroll
    for (int i = 0; i < 4; ++i)
#pragma unroll
      for (int j = 0; j < 2; ++j)
        accL[i][j] = __builtin_amdgcn_mfma_f32_16x16x32_f16(a0[i], b1[j], accL[i][j], 0, 0, 0);
    __builtin_amdgcn_s_setprio(0);
    if (kt + 1 < KT) {
      if (kt + 2 < KT)
        asm volatile("s_waitcnt vmcnt(4)" ::: "memory");
      else
        asm volatile("s_waitcnt vmcnt(0)" ::: "memory");
      __builtin_amdgcn_sched_barrier(0);
      __builtin_amdgcn_s_barrier();
      __builtin_amdgcn_sched_barrier(0);
    }
    scur = (scur + 1 == 3) ? 0 : scur + 1;
  }
  // epilogue: D layout col(lane&15)=n, row((lane>>4)*4+reg)=m
#pragma unroll
  for (int j = 0; j < 2; ++j) {
    const int n = n0 + wn + j * 16 + lr;
    if (n < N) {
      const float bz = bias[n];
#pragma unroll
      for (int i = 0; i < 4; ++i) {
        const int mb = m0 + wm + i * 16 + lc * 4;
#pragma unroll
        for (int r = 0; r < 4; ++r)
          C[(size_t)(mb + r) * (size_t)ldc + n] =
              accM[i][j][r] + 0.00048828125f * accL[i][j][r] + bz;
      }
    }
  }
}

// ---------- 2b) fused tail: row-LN + GELU + fp32 64x64 GEMM + noisy top-2 ----------
// Same 64-row/block partition as the old gemm64_ln + final pair; clean tile
// stays in LDS (scln), saving the cln global round-trip and one launch.
__global__ __launch_bounds__(256, 4) void tail_kernel(
    const float* __restrict__ Zraw, const float* __restrict__ gamma,
    const float* __restrict__ beta, const float* __restrict__ W,
    const float* __restrict__ bias,
    const float* __restrict__ rp4, const float* __restrict__ nsc,
    const float* __restrict__ noise, const float* __restrict__ spec,
    float* __restrict__ out, float* __restrict__ pg, float* __restrict__ pl) {
  const int K = 580;
  __shared__ float As[16][68];
  __shared__ float Bs[16][68];
  __shared__ float sg[580], sb[580], smu[64], srs[64];
  __shared__ float scln[64][66];   // padded: write phase conflict-light
  __shared__ float sgp[4][64], slp[4][64];
  const int t = threadIdx.x;
  const int m0 = blockIdx.x * 64;
  for (int i = t; i < 580; i += 256) { sg[i] = gamma[i]; sb[i] = beta[i]; }
  const int r = t >> 2, q = t & 3;
  const float* zr = Zraw + (size_t)(m0 + r) * K;
  float s0 = 0.f, s1 = 0.f, ss0 = 0.f, ss1 = 0.f;
  for (int j = q; j < 145; j += 8) {
    const float4 u = *(const float4*)(zr + j * 4);
    s0 += u.x + u.y + u.z + u.w;
    ss0 += u.x * u.x + u.y * u.y + u.z * u.z + u.w * u.w;
  }
  for (int j = q + 4; j < 145; j += 8) {
    const float4 u = *(const float4*)(zr + j * 4);
    s1 += u.x + u.y + u.z + u.w;
    ss1 += u.x * u.x + u.y * u.y + u.z * u.z + u.w * u.w;
  }
  float s = s0 + s1, ss = ss0 + ss1;
  s += __shfl_xor(s, 1); s += __shfl_xor(s, 2);
  ss += __shfl_xor(ss, 1); ss += __shfl_xor(ss, 2);
  const float mu = s * (1.f / 580.f);
  const float var = fmaxf(ss * (1.f / 580.f) - mu * mu, 0.f);
  if (q == 0) { smu[r] = mu; srs[r] = 1.f / sqrtf(var + 1e-5f); }
  __syncthreads();

  const int tx = t & 15, ty = t >> 4;
  float acc[4][4] = {};
  for (int kt = 0; kt < 37; ++kt) {
    const int k = kt * 16 + (q << 2);
    float4 va = {0.f, 0.f, 0.f, 0.f}, vb = {0.f, 0.f, 0.f, 0.f};
    if (k < K) {
      const float4 z = *(const float4*)(zr + k);
      const float m_ = smu[r], rs = srs[r];
      va.x = gelu_exact((z.x - m_) * rs * sg[k + 0] + sb[k + 0]);
      va.y = gelu_exact((z.y - m_) * rs * sg[k + 1] + sb[k + 1]);
      va.z = gelu_exact((z.z - m_) * rs * sg[k + 2] + sb[k + 2]);
      va.w = gelu_exact((z.w - m_) * rs * sg[k + 3] + sb[k + 3]);
      vb = *(const float4*)(W + (size_t)r * K + k);
    }
    __syncthreads();
    const int skc = q << 2;
    As[skc + 0][r] = va.x; As[skc + 1][r] = va.y;
    As[skc + 2][r] = va.z; As[skc + 3][r] = va.w;
    Bs[skc + 0][r] = vb.x; Bs[skc + 1][r] = vb.y;
    Bs[skc + 2][r] = vb.z; Bs[skc + 3][r] = vb.w;
    __syncthreads();
#pragma unroll
    for (int kk = 0; kk < 16; ++kk) {
      const float4 a = *(const float4*)&As[kk][ty << 2];
      const float4 b = *(const float4*)&Bs[kk][tx << 2];
      const float aa[4] = {a.x, a.y, a.z, a.w};
      const float bb[4] = {b.x, b.y, b.z, b.w};
#pragma unroll
      for (int i = 0; i < 4; ++i)
#pragma unroll
        for (int j = 0; j < 4; ++j) acc[i][j] = fmaf(aa[i], bb[j], acc[i][j]);
    }
  }
  const float4 bz = *(const float4*)(bias + (tx << 2));
#pragma unroll
  for (int i = 0; i < 4; ++i) {
    scln[(ty << 2) + i][(tx << 2) + 0] = acc[i][0] + bz.x;
    scln[(ty << 2) + i][(tx << 2) + 1] = acc[i][1] + bz.y;
    scln[(ty << 2) + i][(tx << 2) + 2] = acc[i][2] + bz.z;
    scln[(ty << 2) + i][(tx << 2) + 3] = acc[i][3] + bz.w;
  }
  __syncthreads();

  // ---- final phase: +rp*spec^T, noise, top-2, gates, partials ----
  const int w = t >> 6, e = t & 63;
  const float4 sp = *(const float4*)(spec + e * 4);
  float accg = 0.f, accl = 0.f;
  for (int it = 0; it < 16; ++it) {
    const int lrow = it * 4 + w;
    const int row = m0 + lrow;
    const float4 rp = *(const float4*)(rp4 + (size_t)row * 4);
    float c = scln[lrow][e];
    c += rp.x * sp.x + rp.y * sp.y + rp.z * sp.z + rp.w * sp.w;
    const float nv = noise[(size_t)row * 64 + e];
    const float noisy = c + nv * nsc[row];
    float v = noisy;
    int ix = e;
#pragma unroll
    for (int off = 32; off; off >>= 1) {
      const float ov = __shfl_xor(v, off);
      const int oi = __shfl_xor(ix, off);
      if (ov > v || (ov == v && oi < ix)) { v = ov; ix = oi; }
    }
    const float v1 = v;
    const int i1 = ix;
    float v2 = (e == i1) ? -FLT_MAX : noisy;
    int ix2 = e;
#pragma unroll
    for (int off = 32; off; off >>= 1) {
      const float ov = __shfl_xor(v2, off);
      const int oi = __shfl_xor(ix2, off);
      if (ov > v2 || (ov == v2 && oi < ix2)) { v2 = ov; ix2 = oi; }
    }
    const int i2 = ix2;
    if (e == 0) {
      const float texp = expf(v2 - v1);
      const float tw0 = 1.f / (1.f + texp);
      out[(size_t)row * 2 + 0] = tw0;
      out[(size_t)row * 2 + 1] = texp * tw0;
      out[32768 + (size_t)row * 2 + 0] = (float)i1;
      out[32768 + (size_t)row * 2 + 1] = (float)i2;
    }
    const float mx = wmax64(c);
    const float p = expf(c - mx);
    const float ssum = wsum64(p);
    accg += p / ssum;
    accl += (e == i1 || e == i2) ? 1.f : 0.f;
  }
  sgp[w][e] = accg;
  slp[w][e] = accl;
  __syncthreads();
  if (t < 64) {
    pg[blockIdx.x * 64 + t] = sgp[0][t] + sgp[1][t] + sgp[2][t] + sgp[3][t];
    pl[blockIdx.x * 64 + t] = slp[0][t] + slp[1][t] + slp[2][t] + slp[3][t];
  }
}

// ---------- 3) row LN + exact GELU -> swizzled planes (z1); 1 wave = 1 row ----------
__global__ __launch_bounds__(256) void ln_gelu_split_v3(
    const float* __restrict__ Z, const float* __restrict__ gamma,
    const float* __restrict__ beta, unsigned short* __restrict__ P) {
  const int N = 1160, KT = 38;
  __shared__ float srow[4][1160];
  const int t = threadIdx.x, w = t >> 6, l = t & 63;
  const size_t row = (size_t)blockIdx.x * 4 + w;
  const float* zr = Z + row * N;
  float4 v[5];
  float s = 0.f;
#pragma unroll
  for (int c = 0; c < 5; ++c) {
    const int i4 = l + c * 64;
    if (i4 < 290) {
      v[c] = *(const float4*)(zr + i4 * 4);
      *(float4*)&srow[w][i4 * 4] = v[c];
      s += v[c].x + v[c].y + v[c].z + v[c].w;
    } else {
      v[c] = {0.f, 0.f, 0.f, 0.f};
    }
  }
  s = wsum64(s);
  const float mu = s * (1.f / 1160.f);
  float q = 0.f;
#pragma unroll
  for (int c = 0; c < 5; ++c) {
    const int i4 = l + c * 64;
    if (i4 < 290) {
      const float dx = v[c].x - mu, dy = v[c].y - mu, dz = v[c].z - mu, dw = v[c].w - mu;
      q += dx * dx + dy * dy + dz * dz + dw * dw;
    }
  }
  q = wsum64(q);
  const float rstd = 1.f / sqrtf(q * (1.f / 1160.f) + 1e-5f);
  __syncthreads();
  for (int ch = l; ch < 152; ch += 64) {
    const int kt = ch >> 2, c = ch & 3;
    float vv[8];
#pragma unroll
    for (int s2 = 0; s2 < 8; ++s2) {
      const int k = kt * 32 + c * 8 + s2;
      float g = 0.f;
      if (k < N) {
        const float y = (srow[w][k] - mu) * rstd * gamma[k] + beta[k];
        g = gelu_exact(y);
      }
      vv[s2] = g;
    }
    write_chunks(P, row, KT, kt, c, vv);
  }
}

// ---------- 5) aux loss ----------
__global__ void loss_kernel(const float* __restrict__ pg,
                            const float* __restrict__ pl,
                            float* __restrict__ out) {
  const int e = threadIdx.x;  // 64 threads
  float g = 0.f, l = 0.f;
  for (int b = 0; b < 256; ++b) {
    g += pg[b * 64 + e];
    l += pl[b * 64 + e];
  }
  const float prob = g * (1.f / 16384.f);
  const float ld = l * (1.f / 16384.f);
  const float load_loss = 64.f * wsum64(prob * ld);
  const float sgs = wsum64(g);
  const float mean = sgs * (1.f / 64.f);
  const float d = g - mean;
  const float var = wsum64(d * d) * (1.f / 63.f);
  if (e == 0) out[65536] = 0.01f * load_loss + 0.01f * (var / mean);
}

extern "C" void kernel_launch(void* const* d_in, const int* in_sizes, int n_in,
                              void* d_out, int out_size, void* d_ws, size_t ws_size,
                              hipStream_t stream) {
  (void)in_sizes; (void)n_in; (void)out_size; (void)ws_size;
  const float* x = (const float*)d_in[0];
  const float* noise = (const float*)d_in[1];
  const float* vol_w = (const float*)d_in[2];
  const float* vol_b = (const float*)d_in[3];
  const float* vol_g = (const float*)d_in[4];
  const float* vol_bb = (const float*)d_in[5];
  const float* trend_w = (const float*)d_in[6];
  const float* trend_b = (const float*)d_in[7];
  const float* trend_g = (const float*)d_in[8];
  const float* trend_bb = (const float*)d_in[9];
  const float* mom_w = (const float*)d_in[10];
  const float* mom_b = (const float*)d_in[11];
  const float* mom_g = (const float*)d_in[12];
  const float* mom_bb = (const float*)d_in[13];
  const float* reg_w = (const float*)d_in[14];
  const float* reg_b = (const float*)d_in[15];
  const float* reg_g = (const float*)d_in[16];
  const float* reg_bb = (const float*)d_in[17];
  const float* rc1_w = (const float*)d_in[18];
  const float* rc1_b = (const float*)d_in[19];
  const float* rc2_w = (const float*)d_in[20];
  const float* rc2_b = (const float*)d_in[21];
  const float* g1_w = (const float*)d_in[22];
  const float* g1_b = (const float*)d_in[23];
  const float* g1_g = (const float*)d_in[24];
  const float* g1_bb = (const float*)d_in[25];
  const float* g2_w = (const float*)d_in[26];
  const float* g2_b = (const float*)d_in[27];
  const float* g2_g = (const float*)d_in[28];
  const float* g2_bb = (const float*)d_in[29];
  const float* g3_w = (const float*)d_in[30];
  const float* g3_b = (const float*)d_in[31];
  const float* ns1_w = (const float*)d_in[32];
  const float* ns1_b = (const float*)d_in[33];
  const float* ns2_w = (const float*)d_in[34];
  const float* ns2_b = (const float*)d_in[35];
  const float* spec = (const float*)d_in[36];
  float* out = (float*)d_out;

  const size_t B = BROWS;
  float* ws = (float*)d_ws;
  float* rp4 = ws;                                    // B*4 f32
  float* nsc = rp4 + B * 4;                           // B f32
  float* z1 = nsc + B;                                // B*1160 f32
  unsigned short* gip = (unsigned short*)(z1 + B * 1160);  // B*1280 ush (KT=20)
  float* z2 = (float*)gip;                            // alias: B*580 f32 (gi dead after G1)
  unsigned short* z1p = gip + B * 1280;               // B*2432 ush (KT=38)
  unsigned short* w1p = z1p + B * 2432;               // 1280*1280 ush
  unsigned short* w2p = w1p + (size_t)1280 * 1280;    // 640*2432 ush
  float* pg = (float*)(w2p + (size_t)640 * 2432);     // 256*64
  float* pl = pg + 256 * 64;                          // 256*64

  hipFuncSetAttribute(reinterpret_cast<const void*>(gemm_fp16x3_v4),
                      hipFuncAttributeMaxDynamicSharedMemorySize, 98304);

  // weights -> swizzled planes (one launch for both)
  split_w_both<<<780, 256, 0, stream>>>(g1_w, w1p, g2_w, w2p);

  encoder_kernel<<<1024, 256, 0, stream>>>(
      x, vol_w, vol_b, vol_g, vol_bb, trend_w, trend_b, trend_g, trend_bb,
      mom_w, mom_b, mom_g, mom_bb, reg_w, reg_b, reg_g, reg_bb,
      rc1_w, rc1_b, rc2_w, rc2_b, ns1_w, ns1_b, ns2_w, ns2_b, rp4, nsc, gip);

  // G1: [16384,640] x [1280,640]^T -> z1 ; tile 128x128, grid 128 m x 10 n = 1280
  gemm_fp16x3_v4<<<1280, 512, 98304, stream>>>(
      gip, w1p, g1_b, z1, 1160, 20, 1160, 10);
  ln_gelu_split_v3<<<4096, 256, 0, stream>>>(z1, g1_g, g1_bb, z1p);

  // G2: [16384,1216] x [640,1216]^T -> z2 ; tile 128x128, grid 128 m x 5 n = 640
  gemm_fp16x3_v4<<<640, 512, 98304, stream>>>(
      z1p, w2p, g2_b, z2, 580, 38, 580, 5);

  // fused tail: LN+GELU+G3+noisy-top2+partials
  tail_kernel<<<256, 256, 0, stream>>>(
      z2, g2_g, g2_bb, g3_w, g3_b, rp4, nsc, noise, spec, out, pg, pl);
  loss_kernel<<<1, 64, 0, stream>>>(pg, pl, out);
}